// Round 5
// baseline (484.137 us; speedup 1.0000x reference)
//
#include <hip/hip_runtime.h>

// Dots1Attention on MI355X (gfx950).
// cvt3(fp32->bf16, fused, 32B/lane) -> GEMM1(qkv, 128^2 m97-structure; V
//   written transposed in epilogue) -> rmsnorm+rope (2-slot/wave, ushort4)
//   -> flash attention (MFMA, no-max softmax, K+V double-buffered) -> GEMM2.
// R1/R2: 256^2 8-phase GEMM template measured 626 TF with and without
// sched_barrier pins — counted-vmcnt overlap does not reproduce at source
// level here (m232 open quadrant). 128^2 2-barrier structure = ~960 TF ceiling.
// R5: norm_rope 8B/lane loads (was 2B scalar, G13); attn K double-buffer so
// K(kt+1)+V(kt+1) prefetches issue together after sync1 and get a full
// iteration of flight time (was: K issued post-sync2, drained ~500cyc later).

#define T_SEQ 2048
#define HID   4096
#define NH    32
#define NKVH  8
#define HD    128
#define QKVN  6144
#define QSZ   4096
#define QKN   5120   // qk buffer row stride (V not stored row-major)

typedef unsigned short u16;
typedef __attribute__((ext_vector_type(8))) short short8;
typedef __attribute__((ext_vector_type(4))) float floatx4;

__device__ __forceinline__ float bf2f(u16 u) {
  union { unsigned int i; float f; } c; c.i = ((unsigned int)u) << 16; return c.f;
}
__device__ __forceinline__ u16 f2bf(float f) {
  union { float f; unsigned int i; } c; c.f = f;
  unsigned int u = c.i;
  return (u16)((u + 0x7FFFu + ((u >> 16) & 1u)) >> 16);  // RNE
}
__device__ __forceinline__ floatx4 mfma16(short8 a, short8 b, floatx4 c) {
  return __builtin_amdgcn_mfma_f32_16x16x32_bf16(a, b, c, 0, 0, 0);
}

#define GLD16(g, l) __builtin_amdgcn_global_load_lds( \
    (__attribute__((address_space(1))) unsigned int*)(g), \
    (__attribute__((address_space(3))) unsigned int*)(l), 16, 0, 0)

// ---------------------------------------------------------------- cvt f32->bf16 x3
// 8 floats per lane per step: 2x float4 read (32B), 1x uint4 write (16B).
// n0/n1/n2 are in 8-float groups.
__global__ __launch_bounds__(256) void cvt3_kernel(
    const float* __restrict__ s0, const float* __restrict__ s1,
    const float* __restrict__ s2, u16* __restrict__ d0, u16* __restrict__ d1,
    u16* __restrict__ d2, int n0, int n1, int n2) {
  int total = n0 + n1 + n2;
  int stride = gridDim.x * 256;
  for (int i = blockIdx.x * 256 + threadIdx.x; i < total; i += stride) {
    const float* s; u16* d; int j = i;
    if (j < n0)           { s = s0; d = d0; }
    else if (j < n0 + n1) { j -= n0; s = s1; d = d1; }
    else                  { j -= n0 + n1; s = s2; d = d2; }
    float4 a = ((const float4*)s)[2 * j];
    float4 b = ((const float4*)s)[2 * j + 1];
    union { ushort u[8]; uint4 v; } o;
    o.u[0] = f2bf(a.x); o.u[1] = f2bf(a.y); o.u[2] = f2bf(a.z); o.u[3] = f2bf(a.w);
    o.u[4] = f2bf(b.x); o.u[5] = f2bf(b.y); o.u[6] = f2bf(b.z); o.u[7] = f2bf(b.w);
    ((uint4*)d)[j] = o.v;
  }
}

// ---------------------------------------------------------------- GEMM  C = A * B^T
// A[M][K], B[N][K] bf16 row-major. 128x128 tile, BK=64, 4 waves x 64x64.
// LDS layout: per 128-row tile, row m has 8 chunks of 8 bf16; logical chunk c
// lives at physical slot c ^ (m&7). Bank-uniform for GLD16 + ds_read_b128
// (0 conflicts measured). MODE 0: f32 C. MODE 1: bf16 C for cols < 5120;
// cols >= 5120 are V heads, written transposed to VT[kvh][d][t].
template <int MODE>
__global__ __launch_bounds__(256, 2) void gemm_bt(const u16* __restrict__ A,
    const u16* __restrict__ B, void* __restrict__ Cv, u16* __restrict__ VT,
    int mtiles, int K, int ldC) {
  __shared__ __attribute__((aligned(16))) u16 As[128 * 64];
  __shared__ __attribute__((aligned(16))) u16 Bs[128 * 64];
  const int tid = threadIdx.x;
  const int wave = tid >> 6, lane = tid & 63;
  const int lq = lane >> 4, lc = lane & 15;
  const int wm = wave >> 1, wn = wave & 1;
  // XCD-aware bijective swizzle (grid % 8 == 0), then col-major decompose
  // (consecutive ids share the B tile -> per-XCD L2 locality).
  const int id = ((int)blockIdx.x & 7) * ((int)gridDim.x >> 3) + ((int)blockIdx.x >> 3);
  const int by = id % mtiles, bx = id / mtiles;
  const int m0 = by * 128, n0 = bx * 128;

  floatx4 acc[4][4];
#pragma unroll
  for (int i = 0; i < 4; ++i)
#pragma unroll
    for (int j = 0; j < 4; ++j) acc[i][j] = {0.f, 0.f, 0.f, 0.f};

  int arow[4], brow[4];
#pragma unroll
  for (int i = 0; i < 4; ++i) {
    arow[i] = wm * 64 + i * 16 + lc;
    brow[i] = wn * 64 + i * 16 + lc;
  }

  const u16* asrc[4]; const u16* bsrc[4];
#pragma unroll
  for (int r = 0; r < 4; ++r) {
    int L = r * 256 + tid;
    int mm = L >> 3;
    int cc = (L & 7) ^ (mm & 7);
    asrc[r] = A + (size_t)(m0 + mm) * K + cc * 8;
    bsrc[r] = B + (size_t)(n0 + mm) * K + cc * 8;
  }

  for (int k0 = 0; k0 < K; k0 += 64) {
#pragma unroll
    for (int r = 0; r < 4; ++r) {
      GLD16(asrc[r] + k0, As + (r * 256 + wave * 64) * 8);
      GLD16(bsrc[r] + k0, Bs + (r * 256 + wave * 64) * 8);
    }
    __syncthreads();
#pragma unroll
    for (int kb = 0; kb < 2; ++kb) {
      short8 af[4], bfr[4];
#pragma unroll
      for (int mi = 0; mi < 4; ++mi)
        af[mi] = *(const short8*)&As[arow[mi] * 64 + (((kb * 4 + lq) ^ (arow[mi] & 7)) * 8)];
#pragma unroll
      for (int ni = 0; ni < 4; ++ni)
        bfr[ni] = *(const short8*)&Bs[brow[ni] * 64 + (((kb * 4 + lq) ^ (brow[ni] & 7)) * 8)];
#pragma unroll
      for (int mi = 0; mi < 4; ++mi)
#pragma unroll
        for (int ni = 0; ni < 4; ++ni)
          acc[mi][ni] = mfma16(af[mi], bfr[ni], acc[mi][ni]);
    }
    __syncthreads();
  }

  // C/D layout: row = lq*4 + r, col = lc (m89/m91-verified)
  if (MODE == 1 && n0 >= 5120) {  // V heads -> VT[kvh][d][t], 4 t packed
#pragma unroll
    for (int mi = 0; mi < 4; ++mi) {
      int row = m0 + wm * 64 + mi * 16 + lq * 4;  // t, multiple of 4
#pragma unroll
      for (int ni = 0; ni < 4; ++ni) {
        int rel = n0 + wn * 64 + ni * 16 + lc - 5120;
        ushort4 u;
        u.x = f2bf(acc[mi][ni][0]); u.y = f2bf(acc[mi][ni][1]);
        u.z = f2bf(acc[mi][ni][2]); u.w = f2bf(acc[mi][ni][3]);
        *(ushort4*)&VT[(size_t)rel * T_SEQ + row] = u;  // rel = kvh*128 + d
      }
    }
  } else {
#pragma unroll
    for (int mi = 0; mi < 4; ++mi) {
      int row = m0 + wm * 64 + mi * 16 + lq * 4;
#pragma unroll
      for (int ni = 0; ni < 4; ++ni) {
        int col = n0 + wn * 64 + ni * 16 + lc;
#pragma unroll
        for (int r = 0; r < 4; ++r) {
          if (MODE == 1)
            ((u16*)Cv)[(size_t)(row + r) * ldC + col] = f2bf(acc[mi][ni][r]);
          else
            ((float*)Cv)[(size_t)(row + r) * ldC + col] = acc[mi][ni][r];
        }
      }
    }
  }
}

// ---------------------------------------------------------------- RMSNorm + RoPE
// grid (T), block 256. Each wave processes a PAIR of head-slots per iteration
// (5 iterations cover 40 slots): lanes 0-31 slot p, lanes 32-63 slot p+1.
// Lane owns 4 dims (ushort4, 8B/lane — G13). RoPE partner dim d^64 lives in
// lane l^16 (one shfl). Reduction masks 1..16 stay within the 32-lane slot
// group. cos/sin (4 pairs/lane) hoisted. Q scaled by 1/sqrt(HD).
// Slot pairing (p = w*2 + it*8) never straddles the q/k boundary.
__global__ __launch_bounds__(256) void norm_rope_kernel(const u16* __restrict__ qk,
    const float* __restrict__ qw, const float* __restrict__ kw,
    u16* __restrict__ Qo, u16* __restrict__ Ko) {
  const int t = blockIdx.x;
  const int w = threadIdx.x >> 6;
  const int l = threadIdx.x & 63;
  const int half = l >> 5;
  const int d0 = (l & 31) * 4;          // dims d0..d0+3
  const int fi = d0 & 63;               // freq index base
  float c4[4], s4[4];
#pragma unroll
  for (int j = 0; j < 4; ++j) {
    float invf = exp2f((float)(fi + j) * -0.20762050593045158f);  // 10000^-(fi+j)/64
    __sincosf((float)t * invf, &s4[j], &c4[j]);
  }
  const bool hi = (d0 >= 64);
  const u16* row = qk + (size_t)t * QKN;
#pragma unroll
  for (int it = 0; it < 5; ++it) {
    const int p = w * 2 + it * 8;       // first slot of this wave's pair
    const int hs = p + half;
    const bool isq = p < NH;            // wave-uniform
    const float* wptr = isq ? qw : kw;
    float4 wv = *(const float4*)(wptr + d0);
    ushort4 xv = *(const ushort4*)(row + hs * HD + d0);
    float x0 = bf2f(xv.x), x1 = bf2f(xv.y), x2 = bf2f(xv.z), x3 = bf2f(xv.w);
    float ss = x0 * x0 + x1 * x1 + x2 * x2 + x3 * x3;
#pragma unroll
    for (int m = 1; m < 32; m <<= 1) ss += __shfl_xor(ss, m);
    float rstd = rsqrtf(ss * (1.0f / HD) + 1e-6f);
    float n0 = x0 * rstd * wv.x;
    float n1 = x1 * rstd * wv.y;
    float n2 = x2 * rstd * wv.z;
    float n3 = x3 * rstd * wv.w;
    float p0 = __shfl_xor(n0, 16);      // partner dims d0^64..d0^64+3
    float p1 = __shfl_xor(n1, 16);
    float p2 = __shfl_xor(n2, 16);
    float p3 = __shfl_xor(n3, 16);
    float o0, o1, o2, o3;
    if (!hi) {                          // d < 64: n*c - partner*s
      o0 = n0 * c4[0] - p0 * s4[0];
      o1 = n1 * c4[1] - p1 * s4[1];
      o2 = n2 * c4[2] - p2 * s4[2];
      o3 = n3 * c4[3] - p3 * s4[3];
    } else {                            // d >= 64: n*c + partner*s
      o0 = n0 * c4[0] + p0 * s4[0];
      o1 = n1 * c4[1] + p1 * s4[1];
      o2 = n2 * c4[2] + p2 * s4[2];
      o3 = n3 * c4[3] + p3 * s4[3];
    }
    ushort4 ov;
    if (isq) {
      const float sc = 0.08838834764831845f;  // 1/sqrt(128)
      ov.x = f2bf(o0 * sc); ov.y = f2bf(o1 * sc);
      ov.z = f2bf(o2 * sc); ov.w = f2bf(o3 * sc);
      *(ushort4*)(Qo + ((size_t)hs * T_SEQ + t) * HD + d0) = ov;
    } else {
      ov.x = f2bf(o0); ov.y = f2bf(o1); ov.z = f2bf(o2); ov.w = f2bf(o3);
      *(ushort4*)(Ko + ((size_t)(hs - NH) * T_SEQ + t) * HD + d0) = ov;
    }
  }
}

// ---------------------------------------------------------------- flash attention
// K and V both double-buffered in LDS (80 KB/block, 2 blocks/CU = 160 KB).
// Both prefetches for kt+1 issue together right after sync1 -> a full
// iteration (QK + P + sync2 + PV) of flight time before the next sync1 drain.
__global__ __launch_bounds__(256, 2) void attn_kernel(const u16* __restrict__ Qg,
    const u16* __restrict__ Kg, const u16* __restrict__ VTg, u16* __restrict__ Og) {
  __shared__ __attribute__((aligned(16))) u16 Ks[2][8192];
  __shared__ __attribute__((aligned(16))) u16 Vs[2][8192];
  __shared__ __attribute__((aligned(16))) u16 Ps[8192];

  const int bid = blockIdx.x;
  const int h = bid & 31;
  const int qq = bid >> 5;
  const int qt = (qq < 8) ? (15 - qq) : (qq - 8);
  const int kvh = h >> 2;
  const int tid = threadIdx.x;
  const int wave = tid >> 6, lane = tid & 63;
  const int lq = lane >> 4, lc = lane & 15;

  const u16* kbase[4];
  const u16* vbase[4];
#pragma unroll
  for (int i = 0; i < 4; ++i) {
    int L = i * 256 + tid;
    int s = L >> 4, cp = L & 15;
    kbase[i] = Kg + ((size_t)kvh * T_SEQ + s) * HD + ((cp ^ (s & 15)) * 8);
    int d = L >> 3, cv = L & 7;
    vbase[i] = VTg + ((size_t)kvh * HD + d) * T_SEQ + ((cv ^ (d & 7)) * 8);
  }

  short8 qf[2][4];
#pragma unroll
  for (int mb = 0; mb < 2; ++mb)
#pragma unroll
    for (int ks = 0; ks < 4; ++ks) {
      int t = qt * 128 + wave * 32 + mb * 16 + lc;
      qf[mb][ks] = *(const short8*)&Qg[((size_t)h * T_SEQ + t) * HD + ks * 32 + lq * 8];
    }

  short8 ones;
#pragma unroll
  for (int j = 0; j < 8; ++j) ones[j] = (short)0x3F80;  // bf16 1.0

  floatx4 of[2][8];
  floatx4 lacc[2];
#pragma unroll
  for (int mb = 0; mb < 2; ++mb) {
    lacc[mb] = {0.f, 0.f, 0.f, 0.f};
#pragma unroll
    for (int db = 0; db < 8; ++db) of[mb][db] = {0.f, 0.f, 0.f, 0.f};
  }

  const int ktmax = 2 * qt + 1;
  const int t0g = qt * 128 + wave * 32;
  const int wave_tmax = t0g + 31;

#pragma unroll
  for (int i = 0; i < 4; ++i) {
    GLD16(kbase[i], Ks[0] + (i * 256 + wave * 64) * 8);
    GLD16(vbase[i], Vs[0] + (i * 256 + wave * 64) * 8);
  }

  for (int kt = 0; kt <= ktmax; ++kt) {
    __syncthreads();  // drains prefetches issued last iteration
    if (kt + 1 <= ktmax) {
      u16* vd = Vs[(kt + 1) & 1] + (size_t)wave * 64 * 8;
      u16* kd = Ks[(kt + 1) & 1] + (size_t)wave * 64 * 8;
#pragma unroll
      for (int i = 0; i < 4; ++i) {
        GLD16(vbase[i] + (kt + 1) * 64, vd + i * 256 * 8);
        GLD16(kbase[i] + (size_t)(kt + 1) * 8192, kd + i * 256 * 8);
      }
    }
    const bool active = (kt * 64) <= wave_tmax;
    if (active) {
      floatx4 sf[2][4];
#pragma unroll
      for (int mb = 0; mb < 2; ++mb)
#pragma unroll
        for (int nb = 0; nb < 4; ++nb) sf[mb][nb] = {0.f, 0.f, 0.f, 0.f};
      const u16* kb = Ks[kt & 1];
#pragma unroll
      for (int ks = 0; ks < 4; ++ks) {
        short8 kf[4];
#pragma unroll
        for (int nb = 0; nb < 4; ++nb)
          kf[nb] = *(const short8*)&kb[(nb * 16 + lc) * 128 + ((4 * ks + lq) ^ lc) * 8];
#pragma unroll
        for (int mb = 0; mb < 2; ++mb)
#pragma unroll
          for (int nb = 0; nb < 4; ++nb)
            sf[mb][nb] = mfma16(kf[nb], qf[mb][ks], sf[mb][nb]);
      }
      const bool nm = (kt * 64 + 63) > t0g;
#pragma unroll
      for (int mb = 0; mb < 2; ++mb) {
        const int trow = wave * 32 + mb * 16 + lc;
        const int tg = qt * 128 + trow;
#pragma unroll
        for (int nb = 0; nb < 4; ++nb) {
          ushort4 u;
          float p0 = __expf(sf[mb][nb][0]);
          float p1 = __expf(sf[mb][nb][1]);
          float p2 = __expf(sf[mb][nb][2]);
          float p3 = __expf(sf[mb][nb][3]);
          if (nm) {
            int sg = kt * 64 + nb * 16 + lq * 4;
            p0 = (sg + 0 <= tg) ? p0 : 0.f;
            p1 = (sg + 1 <= tg) ? p1 : 0.f;
            p2 = (sg + 2 <= tg) ? p2 : 0.f;
            p3 = (sg + 3 <= tg) ? p3 : 0.f;
          }
          u.x = f2bf(p0); u.y = f2bf(p1); u.z = f2bf(p2); u.w = f2bf(p3);
          int c = 2 * nb + (lq >> 1);
          *(ushort4*)&Ps[trow * 64 + ((c ^ (trow & 7)) * 8) + (lq & 1) * 4] = u;
        }
      }
    }
    __syncthreads();  // P visible
    if (active) {
      const u16* vb = Vs[kt & 1];
      short8 pf[2][2];
#pragma unroll
      for (int mb = 0; mb < 2; ++mb)
#pragma unroll
        for (int k2 = 0; k2 < 2; ++k2) {
          int trow = wave * 32 + mb * 16 + lc;
          pf[mb][k2] =
              *(const short8*)&Ps[trow * 64 + (((4 * k2 + lq) ^ (lc & 7)) * 8)];
        }
#pragma unroll
      for (int k2 = 0; k2 < 2; ++k2) {
#pragma unroll
        for (int db = 0; db < 8; ++db) {
          short8 vf =
              *(const short8*)&vb[(db * 16 + lc) * 64 + (((4 * k2 + lq) ^ (lc & 7)) * 8)];
          of[0][db] = mfma16(pf[0][k2], vf, of[0][db]);
          of[1][db] = mfma16(pf[1][k2], vf, of[1][db]);
        }
        lacc[0] = mfma16(pf[0][k2], ones, lacc[0]);
        lacc[1] = mfma16(pf[1][k2], ones, lacc[1]);
      }
    }
  }
#pragma unroll
  for (int mb = 0; mb < 2; ++mb)
#pragma unroll
    for (int r = 0; r < 4; ++r) {
      float inv = 1.f / lacc[mb][r];
      int tg = qt * 128 + wave * 32 + mb * 16 + lq * 4 + r;
#pragma unroll
      for (int db = 0; db < 8; ++db)
        Og[(size_t)tg * QSZ + h * HD + db * 16 + lc] = f2bf(of[mb][db][r] * inv);
    }
}

// ---------------------------------------------------------------- launcher
extern "C" void kernel_launch(void* const* d_in, const int* in_sizes, int n_in,
                              void* d_out, int out_size, void* d_ws, size_t ws_size,
                              hipStream_t stream) {
  (void)in_sizes; (void)n_in; (void)out_size; (void)ws_size;
  const float* hidden = (const float*)d_in[1];
  const float* wqkv   = (const float*)d_in[2];
  const float* wo     = (const float*)d_in[3];
  const float* qw     = (const float*)d_in[4];
  const float* kw     = (const float*)d_in[5];
  float* out = (float*)d_out;
  char* ws = (char*)d_ws;

  // workspace (lifetime-aliased):
  //  [0,16M)    h_bf (dead after GEMM1)  -> attn_bf
  //  [16M,64M)  wq_bf (dead after GEMM1) -> q_bf [16M,32M), k_bf [32M,36M)
  //  [64M,96M)  wo_bf (persists to GEMM2)
  //  [96M,100M) vT_bf (written by GEMM1 epilogue)
  //  [100M,120M) qk_bf (dead after norm_rope)
  u16* h_bf    = (u16*)(ws + 0);
  u16* wq_bf   = (u16*)(ws + 16777216);
  u16* wo_bf   = (u16*)(ws + 67108864);
  u16* vT_bf   = (u16*)(ws + 100663296);
  u16* qk_bf   = (u16*)(ws + 104857600);
  u16* q_bf    = (u16*)(ws + 16777216);
  u16* k_bf    = (u16*)(ws + 33554432);
  u16* attn_bf = (u16*)(ws + 0);

  cvt3_kernel<<<4096, 256, 0, stream>>>(
      hidden, wqkv, wo, h_bf, wq_bf, wo_bf,
      T_SEQ * HID / 8, QKVN * HID / 8, HID * QSZ / 8);

  gemm_bt<1><<<768, 256, 0, stream>>>(h_bf, wq_bf, qk_bf, vT_bf,
                                      T_SEQ / 128, HID, QKN);

  norm_rope_kernel<<<T_SEQ, 256, 0, stream>>>(qk_bf, qw, kw, q_bf, k_bf);

  attn_kernel<<<512, 256, 0, stream>>>(q_bf, k_bf, vT_bf, attn_bf);

  gemm_bt<0><<<512, 256, 0, stream>>>(attn_bf, wo_bf, out, vT_bf,
                                      T_SEQ / 128, HID, QSZ);
}

// Round 6
// 474.141 us; speedup vs baseline: 1.0211x; 1.0211x over previous
//
#include <hip/hip_runtime.h>

// Dots1Attention on MI355X (gfx950).
// cvt2(hidden+wqkv fp32->bf16) -> GEMM1(qkv, 128^2 m97-structure; V written
//   transposed in epilogue; +256 tail blocks convert wo fp32->bf16, riding
//   GEMM1's idle HBM BW and retire-tail) -> rmsnorm+rope (2-slot/wave,
//   ushort4) -> flash attention (MFMA, no-max softmax, V-dbuf; R4 version —
//   R5's K-dbuf pushed LDS to the 160KB cap and regressed) -> GEMM2(128^2).
// R1/R2: 256^2 8-phase GEMM template = 626 TF with/without sched pins; the
// counted-vmcnt overlap does not reproduce at source level (m232 open
// quadrant). 128^2 2-barrier structure = its ~960 TF ceiling.

#define T_SEQ 2048
#define HID   4096
#define NH    32
#define NKVH  8
#define HD    128
#define QKVN  6144
#define QSZ   4096
#define QKN   5120   // qk buffer row stride (V not stored row-major)

typedef unsigned short u16;
typedef __attribute__((ext_vector_type(8))) short short8;
typedef __attribute__((ext_vector_type(4))) float floatx4;

__device__ __forceinline__ float bf2f(u16 u) {
  union { unsigned int i; float f; } c; c.i = ((unsigned int)u) << 16; return c.f;
}
__device__ __forceinline__ u16 f2bf(float f) {
  union { float f; unsigned int i; } c; c.f = f;
  unsigned int u = c.i;
  return (u16)((u + 0x7FFFu + ((u >> 16) & 1u)) >> 16);  // RNE
}
__device__ __forceinline__ floatx4 mfma16(short8 a, short8 b, floatx4 c) {
  return __builtin_amdgcn_mfma_f32_16x16x32_bf16(a, b, c, 0, 0, 0);
}

#define GLD16(g, l) __builtin_amdgcn_global_load_lds( \
    (__attribute__((address_space(1))) unsigned int*)(g), \
    (__attribute__((address_space(3))) unsigned int*)(l), 16, 0, 0)

// ---------------------------------------------------------------- cvt f32->bf16 x2
// 8 floats per lane per step: 2x float4 read (32B), 1x uint4 write (16B).
// n0/n1 are in 8-float groups. (wo is converted inside GEMM1's tail blocks.)
__global__ __launch_bounds__(256) void cvt2_kernel(
    const float* __restrict__ s0, const float* __restrict__ s1,
    u16* __restrict__ d0, u16* __restrict__ d1, int n0, int n1) {
  int total = n0 + n1;
  int stride = gridDim.x * 256;
  for (int i = blockIdx.x * 256 + threadIdx.x; i < total; i += stride) {
    const float* s; u16* d; int j = i;
    if (j < n0) { s = s0; d = d0; }
    else        { j -= n0; s = s1; d = d1; }
    float4 a = ((const float4*)s)[2 * j];
    float4 b = ((const float4*)s)[2 * j + 1];
    union { ushort u[8]; uint4 v; } o;
    o.u[0] = f2bf(a.x); o.u[1] = f2bf(a.y); o.u[2] = f2bf(a.z); o.u[3] = f2bf(a.w);
    o.u[4] = f2bf(b.x); o.u[5] = f2bf(b.y); o.u[6] = f2bf(b.z); o.u[7] = f2bf(b.w);
    ((uint4*)d)[j] = o.v;
  }
}

// ---------------------------------------------------------------- GEMM  C = A * B^T
// A[M][K], B[N][K] bf16 row-major. 128x128 tile, BK=64, 4 waves x 64x64.
// LDS layout: per 128-row tile, row m has 8 chunks of 8 bf16; logical chunk c
// lives at physical slot c ^ (m&7). Bank-uniform for GLD16 + ds_read_b128
// (0 conflicts measured). MODE 0: f32 C. MODE 1: bf16 C for cols < 5120;
// cols >= 5120 are V heads, written transposed to VT[kvh][d][t].
// Blocks with blockIdx.x >= gemm_grid run a grid-stride f32->bf16 convert of
// xsrc->xdst (xgroups 8-float groups) — rides the GEMM's idle HBM BW / tail.
template <int MODE>
__global__ __launch_bounds__(256, 2) void gemm_bt(const u16* __restrict__ A,
    const u16* __restrict__ B, void* __restrict__ Cv, u16* __restrict__ VT,
    int mtiles, int K, int ldC,
    const float* __restrict__ xsrc, u16* __restrict__ xdst, int xgroups,
    int gemm_grid) {
  __shared__ __attribute__((aligned(16))) u16 As[128 * 64];
  __shared__ __attribute__((aligned(16))) u16 Bs[128 * 64];
  const int tid = threadIdx.x;

  if ((int)blockIdx.x >= gemm_grid) {  // tail cvt blocks (block-uniform branch)
    const int nthr = ((int)gridDim.x - gemm_grid) * 256;
    for (int i = ((int)blockIdx.x - gemm_grid) * 256 + tid; i < xgroups; i += nthr) {
      float4 a = ((const float4*)xsrc)[2 * i];
      float4 b = ((const float4*)xsrc)[2 * i + 1];
      union { ushort u[8]; uint4 v; } o;
      o.u[0] = f2bf(a.x); o.u[1] = f2bf(a.y); o.u[2] = f2bf(a.z); o.u[3] = f2bf(a.w);
      o.u[4] = f2bf(b.x); o.u[5] = f2bf(b.y); o.u[6] = f2bf(b.z); o.u[7] = f2bf(b.w);
      ((uint4*)xdst)[i] = o.v;
    }
    return;
  }

  const int wave = tid >> 6, lane = tid & 63;
  const int lq = lane >> 4, lc = lane & 15;
  const int wm = wave >> 1, wn = wave & 1;
  // XCD-aware bijective swizzle (gemm_grid % 8 == 0), then col-major decompose
  // (consecutive ids share the B tile -> per-XCD L2 locality).
  const int id = ((int)blockIdx.x & 7) * (gemm_grid >> 3) + ((int)blockIdx.x >> 3);
  const int by = id % mtiles, bx = id / mtiles;
  const int m0 = by * 128, n0 = bx * 128;

  floatx4 acc[4][4];
#pragma unroll
  for (int i = 0; i < 4; ++i)
#pragma unroll
    for (int j = 0; j < 4; ++j) acc[i][j] = {0.f, 0.f, 0.f, 0.f};

  int arow[4], brow[4];
#pragma unroll
  for (int i = 0; i < 4; ++i) {
    arow[i] = wm * 64 + i * 16 + lc;
    brow[i] = wn * 64 + i * 16 + lc;
  }

  const u16* asrc[4]; const u16* bsrc[4];
#pragma unroll
  for (int r = 0; r < 4; ++r) {
    int L = r * 256 + tid;
    int mm = L >> 3;
    int cc = (L & 7) ^ (mm & 7);
    asrc[r] = A + (size_t)(m0 + mm) * K + cc * 8;
    bsrc[r] = B + (size_t)(n0 + mm) * K + cc * 8;
  }

  for (int k0 = 0; k0 < K; k0 += 64) {
#pragma unroll
    for (int r = 0; r < 4; ++r) {
      GLD16(asrc[r] + k0, As + (r * 256 + wave * 64) * 8);
      GLD16(bsrc[r] + k0, Bs + (r * 256 + wave * 64) * 8);
    }
    __syncthreads();
#pragma unroll
    for (int kb = 0; kb < 2; ++kb) {
      short8 af[4], bfr[4];
#pragma unroll
      for (int mi = 0; mi < 4; ++mi)
        af[mi] = *(const short8*)&As[arow[mi] * 64 + (((kb * 4 + lq) ^ (arow[mi] & 7)) * 8)];
#pragma unroll
      for (int ni = 0; ni < 4; ++ni)
        bfr[ni] = *(const short8*)&Bs[brow[ni] * 64 + (((kb * 4 + lq) ^ (brow[ni] & 7)) * 8)];
#pragma unroll
      for (int mi = 0; mi < 4; ++mi)
#pragma unroll
        for (int ni = 0; ni < 4; ++ni)
          acc[mi][ni] = mfma16(af[mi], bfr[ni], acc[mi][ni]);
    }
    __syncthreads();
  }

  // C/D layout: row = lq*4 + r, col = lc (m89/m91-verified)
  if (MODE == 1 && n0 >= 5120) {  // V heads -> VT[kvh][d][t], 4 t packed
#pragma unroll
    for (int mi = 0; mi < 4; ++mi) {
      int row = m0 + wm * 64 + mi * 16 + lq * 4;  // t, multiple of 4
#pragma unroll
      for (int ni = 0; ni < 4; ++ni) {
        int rel = n0 + wn * 64 + ni * 16 + lc - 5120;
        ushort4 u;
        u.x = f2bf(acc[mi][ni][0]); u.y = f2bf(acc[mi][ni][1]);
        u.z = f2bf(acc[mi][ni][2]); u.w = f2bf(acc[mi][ni][3]);
        *(ushort4*)&VT[(size_t)rel * T_SEQ + row] = u;  // rel = kvh*128 + d
      }
    }
  } else {
#pragma unroll
    for (int mi = 0; mi < 4; ++mi) {
      int row = m0 + wm * 64 + mi * 16 + lq * 4;
#pragma unroll
      for (int ni = 0; ni < 4; ++ni) {
        int col = n0 + wn * 64 + ni * 16 + lc;
#pragma unroll
        for (int r = 0; r < 4; ++r) {
          if (MODE == 1)
            ((u16*)Cv)[(size_t)(row + r) * ldC + col] = f2bf(acc[mi][ni][r]);
          else
            ((float*)Cv)[(size_t)(row + r) * ldC + col] = acc[mi][ni][r];
        }
      }
    }
  }
}

// ---------------------------------------------------------------- RMSNorm + RoPE
// grid (T), block 256. Each wave processes a PAIR of head-slots per iteration
// (5 iterations cover 40 slots): lanes 0-31 slot p, lanes 32-63 slot p+1.
// Lane owns 4 dims (ushort4, 8B/lane — G13). RoPE partner dim d^64 lives in
// lane l^16 (one shfl). Reduction masks 1..16 stay within the 32-lane slot
// group. cos/sin (4 pairs/lane) hoisted. Q scaled by 1/sqrt(HD).
__global__ __launch_bounds__(256) void norm_rope_kernel(const u16* __restrict__ qk,
    const float* __restrict__ qw, const float* __restrict__ kw,
    u16* __restrict__ Qo, u16* __restrict__ Ko) {
  const int t = blockIdx.x;
  const int w = threadIdx.x >> 6;
  const int l = threadIdx.x & 63;
  const int half = l >> 5;
  const int d0 = (l & 31) * 4;          // dims d0..d0+3
  const int fi = d0 & 63;               // freq index base
  float c4[4], s4[4];
#pragma unroll
  for (int j = 0; j < 4; ++j) {
    float invf = exp2f((float)(fi + j) * -0.20762050593045158f);  // 10000^-(fi+j)/64
    __sincosf((float)t * invf, &s4[j], &c4[j]);
  }
  const bool hi = (d0 >= 64);
  const u16* row = qk + (size_t)t * QKN;
#pragma unroll
  for (int it = 0; it < 5; ++it) {
    const int p = w * 2 + it * 8;       // first slot of this wave's pair
    const int hs = p + half;
    const bool isq = p < NH;            // wave-uniform
    const float* wptr = isq ? qw : kw;
    float4 wv = *(const float4*)(wptr + d0);
    ushort4 xv = *(const ushort4*)(row + hs * HD + d0);
    float x0 = bf2f(xv.x), x1 = bf2f(xv.y), x2 = bf2f(xv.z), x3 = bf2f(xv.w);
    float ss = x0 * x0 + x1 * x1 + x2 * x2 + x3 * x3;
#pragma unroll
    for (int m = 1; m < 32; m <<= 1) ss += __shfl_xor(ss, m);
    float rstd = rsqrtf(ss * (1.0f / HD) + 1e-6f);
    float n0 = x0 * rstd * wv.x;
    float n1 = x1 * rstd * wv.y;
    float n2 = x2 * rstd * wv.z;
    float n3 = x3 * rstd * wv.w;
    float p0 = __shfl_xor(n0, 16);      // partner dims d0^64..d0^64+3
    float p1 = __shfl_xor(n1, 16);
    float p2 = __shfl_xor(n2, 16);
    float p3 = __shfl_xor(n3, 16);
    float o0, o1, o2, o3;
    if (!hi) {                          // d < 64: n*c - partner*s
      o0 = n0 * c4[0] - p0 * s4[0];
      o1 = n1 * c4[1] - p1 * s4[1];
      o2 = n2 * c4[2] - p2 * s4[2];
      o3 = n3 * c4[3] - p3 * s4[3];
    } else {                            // d >= 64: n*c + partner*s
      o0 = n0 * c4[0] + p0 * s4[0];
      o1 = n1 * c4[1] + p1 * s4[1];
      o2 = n2 * c4[2] + p2 * s4[2];
      o3 = n3 * c4[3] + p3 * s4[3];
    }
    ushort4 ov;
    if (isq) {
      const float sc = 0.08838834764831845f;  // 1/sqrt(128)
      ov.x = f2bf(o0 * sc); ov.y = f2bf(o1 * sc);
      ov.z = f2bf(o2 * sc); ov.w = f2bf(o3 * sc);
      *(ushort4*)(Qo + ((size_t)hs * T_SEQ + t) * HD + d0) = ov;
    } else {
      ov.x = f2bf(o0); ov.y = f2bf(o1); ov.z = f2bf(o2); ov.w = f2bf(o3);
      *(ushort4*)(Ko + ((size_t)(hs - NH) * T_SEQ + t) * HD + d0) = ov;
    }
  }
}

// ---------------------------------------------------------------- flash attention
// R4 version: K single-buffered (64 KB LDS, safe 2 blocks/CU), V double-
// buffered; V(kt+1) prefetch after sync1, K(kt+1) after sync2.
__global__ __launch_bounds__(256, 2) void attn_kernel(const u16* __restrict__ Qg,
    const u16* __restrict__ Kg, const u16* __restrict__ VTg, u16* __restrict__ Og) {
  __shared__ __attribute__((aligned(16))) u16 Ks[8192];
  __shared__ __attribute__((aligned(16))) u16 Vs[2][8192];
  __shared__ __attribute__((aligned(16))) u16 Ps[8192];

  const int bid = blockIdx.x;
  const int h = bid & 31;
  const int qq = bid >> 5;
  const int qt = (qq < 8) ? (15 - qq) : (qq - 8);
  const int kvh = h >> 2;
  const int tid = threadIdx.x;
  const int wave = tid >> 6, lane = tid & 63;
  const int lq = lane >> 4, lc = lane & 15;

  const u16* kbase[4];
  const u16* vbase[4];
#pragma unroll
  for (int i = 0; i < 4; ++i) {
    int L = i * 256 + tid;
    int s = L >> 4, cp = L & 15;
    kbase[i] = Kg + ((size_t)kvh * T_SEQ + s) * HD + ((cp ^ (s & 15)) * 8);
    int d = L >> 3, cv = L & 7;
    vbase[i] = VTg + ((size_t)kvh * HD + d) * T_SEQ + ((cv ^ (d & 7)) * 8);
  }

  short8 qf[2][4];
#pragma unroll
  for (int mb = 0; mb < 2; ++mb)
#pragma unroll
    for (int ks = 0; ks < 4; ++ks) {
      int t = qt * 128 + wave * 32 + mb * 16 + lc;
      qf[mb][ks] = *(const short8*)&Qg[((size_t)h * T_SEQ + t) * HD + ks * 32 + lq * 8];
    }

  short8 ones;
#pragma unroll
  for (int j = 0; j < 8; ++j) ones[j] = (short)0x3F80;  // bf16 1.0

  floatx4 of[2][8];
  floatx4 lacc[2];
#pragma unroll
  for (int mb = 0; mb < 2; ++mb) {
    lacc[mb] = {0.f, 0.f, 0.f, 0.f};
#pragma unroll
    for (int db = 0; db < 8; ++db) of[mb][db] = {0.f, 0.f, 0.f, 0.f};
  }

  const int ktmax = 2 * qt + 1;
  const int t0g = qt * 128 + wave * 32;
  const int wave_tmax = t0g + 31;

#pragma unroll
  for (int i = 0; i < 4; ++i) {
    GLD16(kbase[i], Ks + (i * 256 + wave * 64) * 8);
    GLD16(vbase[i], Vs[0] + (i * 256 + wave * 64) * 8);
  }

  for (int kt = 0; kt <= ktmax; ++kt) {
    __syncthreads();
    if (kt + 1 <= ktmax) {
      u16* vd = Vs[(kt + 1) & 1] + (size_t)wave * 64 * 8;
#pragma unroll
      for (int i = 0; i < 4; ++i)
        GLD16(vbase[i] + (kt + 1) * 64, vd + i * 256 * 8);
    }
    const bool active = (kt * 64) <= wave_tmax;
    if (active) {
      floatx4 sf[2][4];
#pragma unroll
      for (int mb = 0; mb < 2; ++mb)
#pragma unroll
        for (int nb = 0; nb < 4; ++nb) sf[mb][nb] = {0.f, 0.f, 0.f, 0.f};
#pragma unroll
      for (int ks = 0; ks < 4; ++ks) {
        short8 kf[4];
#pragma unroll
        for (int nb = 0; nb < 4; ++nb)
          kf[nb] = *(const short8*)&Ks[(nb * 16 + lc) * 128 + ((4 * ks + lq) ^ lc) * 8];
#pragma unroll
        for (int mb = 0; mb < 2; ++mb)
#pragma unroll
          for (int nb = 0; nb < 4; ++nb)
            sf[mb][nb] = mfma16(kf[nb], qf[mb][ks], sf[mb][nb]);
      }
      const bool nm = (kt * 64 + 63) > t0g;
#pragma unroll
      for (int mb = 0; mb < 2; ++mb) {
        const int trow = wave * 32 + mb * 16 + lc;
        const int tg = qt * 128 + trow;
#pragma unroll
        for (int nb = 0; nb < 4; ++nb) {
          ushort4 u;
          float p0 = __expf(sf[mb][nb][0]);
          float p1 = __expf(sf[mb][nb][1]);
          float p2 = __expf(sf[mb][nb][2]);
          float p3 = __expf(sf[mb][nb][3]);
          if (nm) {
            int sg = kt * 64 + nb * 16 + lq * 4;
            p0 = (sg + 0 <= tg) ? p0 : 0.f;
            p1 = (sg + 1 <= tg) ? p1 : 0.f;
            p2 = (sg + 2 <= tg) ? p2 : 0.f;
            p3 = (sg + 3 <= tg) ? p3 : 0.f;
          }
          u.x = f2bf(p0); u.y = f2bf(p1); u.z = f2bf(p2); u.w = f2bf(p3);
          int c = 2 * nb + (lq >> 1);
          *(ushort4*)&Ps[trow * 64 + ((c ^ (trow & 7)) * 8) + (lq & 1) * 4] = u;
        }
      }
    }
    __syncthreads();
    if (kt + 1 <= ktmax) {
      u16* kd = Ks + (size_t)wave * 64 * 8;
#pragma unroll
      for (int i = 0; i < 4; ++i)
        GLD16(kbase[i] + (size_t)(kt + 1) * 8192, kd + i * 256 * 8);
    }
    if (active) {
      const u16* vb = Vs[kt & 1];
      short8 pf[2][2];
#pragma unroll
      for (int mb = 0; mb < 2; ++mb)
#pragma unroll
        for (int k2 = 0; k2 < 2; ++k2) {
          int trow = wave * 32 + mb * 16 + lc;
          pf[mb][k2] =
              *(const short8*)&Ps[trow * 64 + (((4 * k2 + lq) ^ (lc & 7)) * 8)];
        }
#pragma unroll
      for (int k2 = 0; k2 < 2; ++k2) {
#pragma unroll
        for (int db = 0; db < 8; ++db) {
          short8 vf =
              *(const short8*)&vb[(db * 16 + lc) * 64 + (((4 * k2 + lq) ^ (lc & 7)) * 8)];
          of[0][db] = mfma16(pf[0][k2], vf, of[0][db]);
          of[1][db] = mfma16(pf[1][k2], vf, of[1][db]);
        }
        lacc[0] = mfma16(pf[0][k2], ones, lacc[0]);
        lacc[1] = mfma16(pf[1][k2], ones, lacc[1]);
      }
    }
  }
#pragma unroll
  for (int mb = 0; mb < 2; ++mb)
#pragma unroll
    for (int r = 0; r < 4; ++r) {
      float inv = 1.f / lacc[mb][r];
      int tg = qt * 128 + wave * 32 + mb * 16 + lq * 4 + r;
#pragma unroll
      for (int db = 0; db < 8; ++db)
        Og[(size_t)tg * QSZ + h * HD + db * 16 + lc] = f2bf(of[mb][db][r] * inv);
    }
}

// ---------------------------------------------------------------- launcher
extern "C" void kernel_launch(void* const* d_in, const int* in_sizes, int n_in,
                              void* d_out, int out_size, void* d_ws, size_t ws_size,
                              hipStream_t stream) {
  (void)in_sizes; (void)n_in; (void)out_size; (void)ws_size;
  const float* hidden = (const float*)d_in[1];
  const float* wqkv   = (const float*)d_in[2];
  const float* wo     = (const float*)d_in[3];
  const float* qw     = (const float*)d_in[4];
  const float* kw     = (const float*)d_in[5];
  float* out = (float*)d_out;
  char* ws = (char*)d_ws;

  // workspace (lifetime-aliased):
  //  [0,16M)    h_bf (dead after GEMM1)  -> attn_bf
  //  [16M,64M)  wq_bf (dead after GEMM1) -> q_bf [16M,32M), k_bf [32M,36M)
  //  [64M,96M)  wo_bf (written by GEMM1 tail blocks; persists to GEMM2)
  //  [96M,100M) vT_bf (written by GEMM1 epilogue)
  //  [100M,120M) qk_bf (dead after norm_rope)
  u16* h_bf    = (u16*)(ws + 0);
  u16* wq_bf   = (u16*)(ws + 16777216);
  u16* wo_bf   = (u16*)(ws + 67108864);
  u16* vT_bf   = (u16*)(ws + 100663296);
  u16* qk_bf   = (u16*)(ws + 104857600);
  u16* q_bf    = (u16*)(ws + 16777216);
  u16* k_bf    = (u16*)(ws + 33554432);
  u16* attn_bf = (u16*)(ws + 0);

  cvt2_kernel<<<4096, 256, 0, stream>>>(
      hidden, wqkv, h_bf, wq_bf, T_SEQ * HID / 8, QKVN * HID / 8);

  // 768 gemm blocks + 256 tail blocks converting wo (16.78M floats).
  gemm_bt<1><<<1024, 256, 0, stream>>>(h_bf, wq_bf, qk_bf, vT_bf,
                                       T_SEQ / 128, HID, QKN,
                                       wo, wo_bf, HID * QSZ / 8, 768);

  norm_rope_kernel<<<T_SEQ, 256, 0, stream>>>(qk_bf, qw, kw, q_bf, k_bf);

  attn_kernel<<<512, 256, 0, stream>>>(q_bf, k_bf, vT_bf, attn_bf);

  gemm_bt<0><<<512, 256, 0, stream>>>(attn_bf, wo_bf, out, vT_bf,
                                      T_SEQ / 128, HID, QSZ,
                                      nullptr, nullptr, 0, 512);
}